// Round 4
// baseline (358.595 us; speedup 1.0000x reference)
//
#include <hip/hip_runtime.h>
#include <hip/hip_bf16.h>
#include <hip/hip_fp8.h>
#include <math.h>

#define NB 4096     // batch (= B); label of row n is labels[n % NB]
#define NN 8192     // N = B * n_views
#define DD 128      // feature dim (bytes per fp8 row)
#define NCLS 100    // label values 0..99
#define NSPLIT 16   // j-splits; 512 cols per block

constexpr float INV_T = 14.285714285714286f;   // 1/0.07 (= subtracted row max M)
constexpr float EC1   = 20.609929155556620f;   // INV_T * log2(e)
constexpr float EC0   = -20.609929155556620f;  // -INV_T * log2(e)
constexpr float LN2   = 0.6931471805599453f;

typedef unsigned char u8;
typedef __attribute__((ext_vector_type(8))) int   v8i;
typedef __attribute__((ext_vector_type(4))) int   v4i;
typedef __attribute__((ext_vector_type(4))) float f32x4;

// fb8 layout is FRAGMENT-MAJOR: 512 groups of 16 rows; group g occupies 2 KB:
//   fb8[g*2048 + h*1024 + (q*16 + n15)*16 + b]
//     = normalized_row(g*16 + n15)[ q*32 + h*16 + b ],  q=0..3, h=0..1, b=0..15
// MFMA A/B operand for row-group g = two coalesced 1KB loads (lane l reads
// base + l*16 and +1024). fb8 is 1 MB, fully L2-resident; no LDS staging.

// ---- kernel 1: L2-normalize rows -> fp8 e4m3 (fragment-major) + selfdot ----
__global__ __launch_bounds__(256) void k_norm(const float* __restrict__ feat,
                                              u8* __restrict__ fb8,
                                              float* __restrict__ selfdot,
                                              float* __restrict__ out) {
    const int gid = blockIdx.x * 256 + threadIdx.x;
    if (gid == 0) out[0] = 0.0f;               // k_final atomicAdds into out
    const int r    = gid >> 6;                 // one wave per row
    const int lane = threadIdx.x & 63;
    const float2 v = ((const float2*)(feat + (size_t)r * DD))[lane];
    float ss = v.x * v.x + v.y * v.y;
#pragma unroll
    for (int off = 1; off < 64; off <<= 1) ss += __shfl_xor(ss, off, 64);
    const float scale = 1.0f / fmaxf(sqrtf(ss), 1e-12f);
    const __hip_fp8_e4m3 qx(v.x * scale), qy(v.y * scale);  // OCP e4m3fn
    const unsigned short pack = (unsigned short)qx.__x |
                                ((unsigned short)qy.__x << 8);
    // lane holds row-bytes 2*lane, 2*lane+1 -> chunk q=lane>>4, h=(lane>>3)&1
    const int g    = r >> 4;
    const int n15r = r & 15;
    const int qc   = lane >> 4;
    const int hc   = (lane >> 3) & 1;
    const int bofs = (2 * lane) & 15;
    *(unsigned short*)(fb8 + (size_t)g * 2048 + hc * 1024 +
                       ((qc * 16 + n15r) << 4) + bofs) = pack;
    // self-dot of the QUANTIZED row (matches the MFMA diagonal)
    const float xb = (float)qx, yb = (float)qy;
    float s2 = xb * xb + yb * yb;
#pragma unroll
    for (int off = 1; off < 64; off <<= 1) s2 += __shfl_xor(s2, off, 64);
    if (lane == 0) selfdot[r] = s2;
}

// ---- kernel 2: F*F^T via MX-fp8 K=128 MFMA, fused exp + masked-possum ----
// Block: 128 rows x 512 cols; 4 waves of 32 rows. Grid 1024 = 64 rb x 16 js.
// Software-pipelined: B-fragments prefetched 2 tiles ahead (issue-early);
// epilogue of tile jt-1 runs while tile jt's MFMAs are in flight (the wave
// never waits on its own MFMA before having VALU work to issue).
__global__ __launch_bounds__(256, 4) void k_main(const u8* __restrict__ fb8,
                                                 const int* __restrict__ labels,
                                                 float* __restrict__ g_se,
                                                 float* __restrict__ g_ps) {
    __shared__ int slab[512];          // labels of this block's col range

    const int tid  = threadIdx.x;
    const int lane = tid & 63;
    const int w    = tid >> 6;                  // 0..3
    const int rb   = blockIdx.x >> 4;           // 0..63
    const int js   = blockIdx.x & (NSPLIT - 1); // 0..15
    const int i0   = rb * 128 + w * 32;
    const int jb0  = js * 512;
    const int q    = lane >> 4;
    const int n15  = lane & 15;

    slab[tid]       = labels[(jb0 + tid) & (NB - 1)];
    slab[tid + 256] = labels[(jb0 + tid + 256) & (NB - 1)];

    // A fragments: 2 row-tiles, full K=128 per tile (8 VGPRs each)
    v8i af[2];
#pragma unroll
    for (int tt = 0; tt < 2; ++tt) {
        const u8* ap = fb8 + (size_t)((i0 >> 4) + tt) * 2048 + lane * 16;
        const v4i lo = *(const v4i*)ap;
        const v4i hi = *(const v4i*)(ap + 1024);
        v8i a;
#pragma unroll
        for (int k = 0; k < 4; ++k) { a[k] = lo[k]; a[4 + k] = hi[k]; }
        af[tt] = a;
    }
    // labels of this lane's 8 accumulator rows (C/D map: row = q*4+r)
    int labi[8];
#pragma unroll
    for (int tt = 0; tt < 2; ++tt)
#pragma unroll
        for (int r = 0; r < 4; ++r)
            labi[tt * 4 + r] = labels[(i0 + tt * 16 + q * 4 + r) & (NB - 1)];

    float a_se[8] = {}, a_ps[8] = {};

    __syncthreads();   // slab ready (only barrier in the kernel)

    const u8* bbase = fb8 + (size_t)(jb0 >> 4) * 2048 + lane * 16;

    // --- prologue: prefetch tiles 0,1; MFMA tile 0 ---
    v4i clo = *(const v4i*)(bbase);
    v4i chi = *(const v4i*)(bbase + 1024);
    v4i nlo = *(const v4i*)(bbase + 2048);
    v4i nhi = *(const v4i*)(bbase + 2048 + 1024);
    f32x4 p0, p1;
    int plab = slab[n15];
    {
        v8i bb;
#pragma unroll
        for (int k = 0; k < 4; ++k) { bb[k] = clo[k]; bb[4 + k] = chi[k]; }
        const f32x4 z = {0.f, 0.f, 0.f, 0.f};
        p0 = __builtin_amdgcn_mfma_scale_f32_16x16x128_f8f6f4(
                 af[0], bb, z, 0, 0, 0, 0x7F7F7F7F, 0, 0x7F7F7F7F);
        p1 = __builtin_amdgcn_mfma_scale_f32_16x16x128_f8f6f4(
                 af[1], bb, z, 0, 0, 0, 0x7F7F7F7F, 0, 0x7F7F7F7F);
    }
    clo = nlo; chi = nhi;

    // --- steady state: prefetch jt+1, MFMA jt, epilogue jt-1 ---
#pragma unroll 4
    for (int jt = 1; jt < 32; ++jt) {
        if (jt + 1 < 32) {
            const u8* np = bbase + (size_t)(jt + 1) * 2048;
            nlo = *(const v4i*)np;
            nhi = *(const v4i*)(np + 1024);
        }
        v8i bb;
#pragma unroll
        for (int k = 0; k < 4; ++k) { bb[k] = clo[k]; bb[4 + k] = chi[k]; }
        const f32x4 z = {0.f, 0.f, 0.f, 0.f};
        const f32x4 c0 = __builtin_amdgcn_mfma_scale_f32_16x16x128_f8f6f4(
                 af[0], bb, z, 0, 0, 0, 0x7F7F7F7F, 0, 0x7F7F7F7F);
        const f32x4 c1 = __builtin_amdgcn_mfma_scale_f32_16x16x128_f8f6f4(
                 af[1], bb, z, 0, 0, 0, 0x7F7F7F7F, 0, 0x7F7F7F7F);
        // epilogue on previous tile's (complete) results — overlaps c0/c1
#pragma unroll
        for (int r = 0; r < 4; ++r) {
            const float d0 = p0[r], d1 = p1[r];
            a_se[r]     += __builtin_amdgcn_exp2f(fmaf(d0, EC1, EC0));
            a_se[4 + r] += __builtin_amdgcn_exp2f(fmaf(d1, EC1, EC0));
            a_ps[r]     += (labi[r]     == plab) ? d0 : 0.0f;
            a_ps[4 + r] += (labi[4 + r] == plab) ? d1 : 0.0f;
        }
        p0 = c0; p1 = c1; plab = slab[jt * 16 + n15];
        clo = nlo; chi = nhi;
    }
    // --- drain: epilogue of tile 31 ---
#pragma unroll
    for (int r = 0; r < 4; ++r) {
        const float d0 = p0[r], d1 = p1[r];
        a_se[r]     += __builtin_amdgcn_exp2f(fmaf(d0, EC1, EC0));
        a_se[4 + r] += __builtin_amdgcn_exp2f(fmaf(d1, EC1, EC0));
        a_ps[r]     += (labi[r]     == plab) ? d0 : 0.0f;
        a_ps[4 + r] += (labi[4 + r] == plab) ? d1 : 0.0f;
    }

    // 16 lanes per quad share the same rows; reduce, single plain store each
#pragma unroll
    for (int s = 0; s < 8; ++s) {
        float v1 = a_se[s], v2 = a_ps[s];
#pragma unroll
        for (int off = 1; off < 16; off <<= 1) {
            v1 += __shfl_xor(v1, off, 64);
            v2 += __shfl_xor(v2, off, 64);
        }
        if (n15 == 0) {
            const int row = i0 + (s >> 2) * 16 + q * 4 + (s & 3);
            g_se[js * NN + row] = v1;
            g_ps[js * NN + row] = v2;
        }
    }
}

// ---- kernel 3: per-row loss; counts via LDS histogram; atomic mean ----
__global__ __launch_bounds__(256) void k_final(const int* __restrict__ labels,
                                               const float* __restrict__ g_se,
                                               const float* __restrict__ g_ps,
                                               const float* __restrict__ selfdot,
                                               float* __restrict__ out) {
    __shared__ int hist[NCLS];
    const int tid = threadIdx.x;
    for (int i = tid; i < NCLS; i += 256) hist[i] = 0;
    __syncthreads();
    for (int b = tid; b < NB; b += 256) atomicAdd(&hist[labels[b]], 1);
    __syncthreads();

    const int r = blockIdx.x * 256 + tid;
    const int c = labels[r & (NB - 1)];
    float se = 0.f, ps = 0.f;
#pragma unroll
    for (int t = 0; t < NSPLIT; ++t) {
        se += g_se[t * NN + r];
        ps += g_ps[t * NN + r];
    }
    const float sd = selfdot[r];
    se -= __builtin_amdgcn_exp2f(fmaf(sd, EC1, EC0));  // drop diagonal from sumexp
    const float ct = (float)(2 * hist[c] - 1);         // positives excl. diagonal
    const float possum = INV_T * ((ps - sd) - ct);     // sum_pos (l_ij - M)
    const float lg  = __builtin_amdgcn_logf(se + 1e-12f) * LN2;
    const float mlpp = (possum - ct * lg) / fmaxf(ct, 1.0f);
    float v = -mlpp * (1.0f / (float)NN);
#pragma unroll
    for (int off = 1; off < 64; off <<= 1) v += __shfl_xor(v, off, 64);
    __shared__ float sred[4];
    if ((tid & 63) == 0) sred[tid >> 6] = v;
    __syncthreads();
    if (tid == 0) atomicAdd(out, sred[0] + sred[1] + sred[2] + sred[3]);
}

extern "C" void kernel_launch(void* const* d_in, const int* in_sizes, int n_in,
                              void* d_out, int out_size, void* d_ws, size_t ws_size,
                              hipStream_t stream) {
    const float* feat = (const float*)d_in[0];
    const int* labels = (const int*)d_in[1];
    float* out        = (float*)d_out;
    char* ws          = (char*)d_ws;

    u8* fb8         = (u8*)ws;                                       // 1 MB fp8 (fragment-major)
    float* g_se     = (float*)(ws + (size_t)1 * 1024 * 1024);        // [16][NN] 512 KB
    float* g_ps     = g_se + NSPLIT * NN;                            // 512 KB
    float* selfdot  = g_ps + NSPLIT * NN;                            // NN f32

    k_norm<<<NN / 4, 256, 0, stream>>>(feat, fb8, selfdot, out);
    k_main<<<(NN / 128) * NSPLIT, 256, 0, stream>>>(fb8, labels, g_se, g_ps);
    k_final<<<NN / 256, 256, 0, stream>>>(labels, g_se, g_ps, selfdot, out);
}

// Round 6
// 143.826 us; speedup vs baseline: 2.4933x; 2.4933x over previous
//
#include <hip/hip_runtime.h>
#include <hip/hip_bf16.h>
#include <hip/hip_fp8.h>
#include <math.h>

#define NB 4096     // batch (= B); label of row n is labels[n % NB]
#define NN 8192     // N = B * n_views
#define DD 128      // feature dim (bytes per fp8 row)
#define NCLS 100    // label values 0..99
#define NSPLIT 16   // j-splits; 512 cols per block
#define NBLK 1024   // k_main grid

constexpr float INV_T = 14.285714285714286f;   // 1/0.07 (= subtracted row max M)
constexpr float EC1   = 20.609929155556620f;   // INV_T * log2(e)
constexpr float EC0   = -20.609929155556620f;  // -INV_T * log2(e)
constexpr float LN2   = 0.6931471805599453f;

typedef unsigned char u8;
typedef __attribute__((ext_vector_type(8))) int   v8i;
typedef __attribute__((ext_vector_type(4))) int   v4i;
typedef __attribute__((ext_vector_type(4))) float f32x4;

// fb8 layout is FRAGMENT-MAJOR: 512 groups of 16 rows; group g occupies 2 KB:
//   fb8[g*2048 + h*1024 + (q*16 + n15)*16 + b]
//     = normalized_row(g*16 + n15)[ q*32 + h*16 + b ],  q=0..3, h=0..1, b=0..15
// MFMA A/B operand for row-group g = two coalesced 1KB loads (lane l reads
// base + l*16 and +1024). fb8 is 1 MB, fully L2-resident; no LDS staging.
//
// 2 dispatches: k_norm (also zeroes accumulators+counter), then k_main with
// per-row atomic accumulation; the LAST block to finish (atomic counter,
// dispatch-order-independent) computes the final loss. No cooperative API
// (R5: hipLaunchCooperativeKernel silently no-ops under graph capture).

// ---- kernel 1: L2-normalize rows -> fp8 e4m3 (fragment-major) + selfdot ----
__global__ __launch_bounds__(256) void k_norm(const float* __restrict__ feat,
                                              u8* __restrict__ fb8,
                                              float* __restrict__ selfdot,
                                              float* __restrict__ se_acc,
                                              float* __restrict__ ps_acc,
                                              unsigned int* __restrict__ counter,
                                              float* __restrict__ out) {
    const int gid = blockIdx.x * 256 + threadIdx.x;
    if (gid == 0) { out[0] = 0.0f; *counter = 0u; }
    if (gid < NN) { se_acc[gid] = 0.0f; ps_acc[gid] = 0.0f; }  // ws is poisoned
    const int r    = gid >> 6;                 // one wave per row
    const int lane = threadIdx.x & 63;
    const float2 v = ((const float2*)(feat + (size_t)r * DD))[lane];
    float ss = v.x * v.x + v.y * v.y;
#pragma unroll
    for (int off = 1; off < 64; off <<= 1) ss += __shfl_xor(ss, off, 64);
    const float scale = 1.0f / fmaxf(sqrtf(ss), 1e-12f);
    const __hip_fp8_e4m3 qx(v.x * scale), qy(v.y * scale);  // OCP e4m3fn
    const unsigned short pack = (unsigned short)qx.__x |
                                ((unsigned short)qy.__x << 8);
    // lane holds row-bytes 2*lane, 2*lane+1 -> chunk q=lane>>4, h=(lane>>3)&1
    const int g    = r >> 4;
    const int n15r = r & 15;
    const int qc   = lane >> 4;
    const int hc   = (lane >> 3) & 1;
    const int bofs = (2 * lane) & 15;
    *(unsigned short*)(fb8 + (size_t)g * 2048 + hc * 1024 +
                       ((qc * 16 + n15r) << 4) + bofs) = pack;
    // self-dot of the QUANTIZED row (matches the MFMA diagonal)
    const float xb = (float)qx, yb = (float)qy;
    float s2 = xb * xb + yb * yb;
#pragma unroll
    for (int off = 1; off < 64; off <<= 1) s2 += __shfl_xor(s2, off, 64);
    if (lane == 0) selfdot[r] = s2;
}

// ---- kernel 2: F*F^T via MX-fp8 K=128 MFMA, fused exp + masked-possum,
//      per-row atomic accumulation, last-block loss finale ----
__global__ __launch_bounds__(256, 4) void k_main(const u8* __restrict__ fb8,
                                                 const int* __restrict__ labels,
                                                 float* __restrict__ se_acc,
                                                 float* __restrict__ ps_acc,
                                                 const float* __restrict__ selfdot,
                                                 unsigned int* __restrict__ counter,
                                                 float* __restrict__ out) {
    __shared__ int slab[512];          // phase2: col labels; finale: hist+sred
    __shared__ int amLast;

    const int tid  = threadIdx.x;
    const int lane = tid & 63;
    const int w    = tid >> 6;                  // 0..3
    const int rb   = blockIdx.x >> 4;           // 0..63
    const int js   = blockIdx.x & (NSPLIT - 1); // 0..15
    const int i0   = rb * 128 + w * 32;
    const int jb0  = js * 512;
    const int q    = lane >> 4;
    const int n15  = lane & 15;

    slab[tid]       = labels[(jb0 + tid) & (NB - 1)];
    slab[tid + 256] = labels[(jb0 + tid + 256) & (NB - 1)];

    // A fragments: 2 row-tiles, full K=128 per tile (8 VGPRs each)
    v8i af[2];
#pragma unroll
    for (int tt = 0; tt < 2; ++tt) {
        const u8* ap = fb8 + (size_t)((i0 >> 4) + tt) * 2048 + lane * 16;
        const v4i lo = *(const v4i*)ap;
        const v4i hi = *(const v4i*)(ap + 1024);
        v8i a;
#pragma unroll
        for (int k = 0; k < 4; ++k) { a[k] = lo[k]; a[4 + k] = hi[k]; }
        af[tt] = a;
    }
    // labels of this lane's 8 accumulator rows (C/D map: row = q*4+r)
    int labi[8];
#pragma unroll
    for (int tt = 0; tt < 2; ++tt)
#pragma unroll
        for (int r = 0; r < 4; ++r)
            labi[tt * 4 + r] = labels[(i0 + tt * 16 + q * 4 + r) & (NB - 1)];

    float a_se[8] = {}, a_ps[8] = {};

    __syncthreads();   // slab ready

    const u8* bbase = fb8 + (size_t)(jb0 >> 4) * 2048 + lane * 16;
#pragma unroll 4
    for (int jt = 0; jt < 32; ++jt) {
        const u8* bp = bbase + (size_t)jt * 2048;
        const v4i lo = *(const v4i*)bp;
        const v4i hi = *(const v4i*)(bp + 1024);
        v8i bb;
#pragma unroll
        for (int k = 0; k < 4; ++k) { bb[k] = lo[k]; bb[4 + k] = hi[k]; }
        const int labj = slab[jt * 16 + n15];
        f32x4 a0 = {0.f, 0.f, 0.f, 0.f}, a1 = {0.f, 0.f, 0.f, 0.f};
        // cbsz=0 (A=fp8 e4m3), blgp=0 (B=fp8); scale bytes 0x7F = e8m0 1.0
        a0 = __builtin_amdgcn_mfma_scale_f32_16x16x128_f8f6f4(
                 af[0], bb, a0, 0, 0, 0, 0x7F7F7F7F, 0, 0x7F7F7F7F);
        a1 = __builtin_amdgcn_mfma_scale_f32_16x16x128_f8f6f4(
                 af[1], bb, a1, 0, 0, 0, 0x7F7F7F7F, 0, 0x7F7F7F7F);
#pragma unroll
        for (int r = 0; r < 4; ++r) {
            const float d0 = a0[r], d1 = a1[r];
            a_se[r]     += __builtin_amdgcn_exp2f(fmaf(d0, EC1, EC0));
            a_se[4 + r] += __builtin_amdgcn_exp2f(fmaf(d1, EC1, EC0));
            a_ps[r]     += (labi[r]     == labj) ? d0 : 0.0f;
            a_ps[4 + r] += (labi[4 + r] == labj) ? d1 : 0.0f;
        }
    }

    // 16 lanes per quad share the same rows; reduce, one atomic each
#pragma unroll
    for (int s = 0; s < 8; ++s) {
        float v1 = a_se[s], v2 = a_ps[s];
#pragma unroll
        for (int off = 1; off < 16; off <<= 1) {
            v1 += __shfl_xor(v1, off, 64);
            v2 += __shfl_xor(v2, off, 64);
        }
        if (n15 == 0) {
            const int row = i0 + (s >> 2) * 16 + q * 4 + (s & 3);
            atomicAdd(&se_acc[row], v1);
            atomicAdd(&ps_acc[row], v2);
        }
    }

    // ---- last-block finale (dispatch-order independent, no spin-wait) ----
    __threadfence();
    __syncthreads();               // vmcnt(0) drain: all block atomics done
    if (tid == 0) amLast = (atomicAdd(counter, 1u) == NBLK - 1u);
    __syncthreads();
    if (!amLast) return;
    __threadfence();               // acquire

    int* hist = slab;              // reuse LDS
    float* sred = (float*)&slab[128];
    for (int i = tid; i < NCLS; i += 256) hist[i] = 0;
    __syncthreads();
    for (int b = tid; b < NB; b += 256) atomicAdd(&hist[labels[b]], 1);
    __syncthreads();

    float acc = 0.0f;
#pragma unroll 4
    for (int it = 0; it < NN / 256; ++it) {
        const int r = it * 256 + tid;
        const int c = labels[r & (NB - 1)];
        float se = __hip_atomic_load(&se_acc[r], __ATOMIC_RELAXED,
                                     __HIP_MEMORY_SCOPE_AGENT);
        float ps = __hip_atomic_load(&ps_acc[r], __ATOMIC_RELAXED,
                                     __HIP_MEMORY_SCOPE_AGENT);
        const float sd = selfdot[r];
        se -= __builtin_amdgcn_exp2f(fmaf(sd, EC1, EC0));  // drop diagonal
        const float ct = (float)(2 * hist[c] - 1);         // positives excl. diag
        const float possum = INV_T * ((ps - sd) - ct);     // sum_pos (l_ij - M)
        const float lg  = __builtin_amdgcn_logf(se + 1e-12f) * LN2;
        const float mlpp = (possum - ct * lg) / fmaxf(ct, 1.0f);
        acc += -mlpp * (1.0f / (float)NN);
    }
#pragma unroll
    for (int off = 1; off < 64; off <<= 1) acc += __shfl_xor(acc, off, 64);
    if ((tid & 63) == 0) sred[tid >> 6] = acc;
    __syncthreads();
    if (tid == 0) out[0] = sred[0] + sred[1] + sred[2] + sred[3];
}

extern "C" void kernel_launch(void* const* d_in, const int* in_sizes, int n_in,
                              void* d_out, int out_size, void* d_ws, size_t ws_size,
                              hipStream_t stream) {
    const float* feat = (const float*)d_in[0];
    const int* labels = (const int*)d_in[1];
    float* out        = (float*)d_out;
    char* ws          = (char*)d_ws;

    u8* fb8              = (u8*)ws;                                  // 1 MB fp8 (fragment-major)
    float* se_acc        = (float*)(ws + (size_t)1 * 1024 * 1024);   // NN f32
    float* ps_acc        = se_acc + NN;                              // NN f32
    float* selfdot       = ps_acc + NN;                              // NN f32
    unsigned int* counter = (unsigned int*)(selfdot + NN);

    k_norm<<<NN / 4, 256, 0, stream>>>(feat, fb8, selfdot, se_acc, ps_acc,
                                       counter, out);
    k_main<<<NBLK, 256, 0, stream>>>(fb8, labels, se_acc, ps_acc, selfdot,
                                     counter, out);
}

// Round 7
// 95.020 us; speedup vs baseline: 3.7739x; 1.5136x over previous
//
#include <hip/hip_runtime.h>
#include <hip/hip_bf16.h>
#include <hip/hip_fp8.h>
#include <math.h>

#define NB 4096     // batch (= B); label of row n is labels[n % NB]
#define NN 8192     // N = B * n_views
#define DD 128      // feature dim (bytes per fp8 row)
#define NCLS 100    // label values 0..99
#define NSPLIT 32   // j-splits; 256 cols per block -> 2048 blocks = 8/CU (100% occ)

constexpr float INV_T = 14.285714285714286f;   // 1/0.07 (= subtracted row max M)
constexpr float EC1   = 20.609929155556620f;   // INV_T * log2(e)
constexpr float EC0   = -20.609929155556620f;  // -INV_T * log2(e)
constexpr float LN2   = 0.6931471805599453f;

typedef unsigned char u8;
typedef __attribute__((ext_vector_type(8))) int   v8i;
typedef __attribute__((ext_vector_type(4))) int   v4i;
typedef __attribute__((ext_vector_type(4))) float f32x4;

// fb8 layout is FRAGMENT-MAJOR: 512 groups of 16 rows; group g occupies 2 KB:
//   fb8[g*2048 + h*1024 + (q*16 + n15)*16 + b]
//     = normalized_row(g*16 + n15)[ q*32 + h*16 + b ],  q=0..3, h=0..1, b=0..15
// MFMA A/B operand for row-group g = two coalesced 1KB loads (lane l reads
// base + l*16 and +1024). fb8 is 1 MB, fully L2-resident; no LDS staging.
//
// R6 lesson: k_main is LATENCY-bound (MfmaUtil 3.6%, VALUBusy 13%, occ 26%).
// Fix = TLP: 2048 blocks (8/CU, 32 waves/CU). No fences/atomics (R6 regression);
// plain per-split stores + separate k_final (R2 structure, best verified).

// ---- kernel 1: L2-normalize rows -> fp8 e4m3 (fragment-major) + selfdot ----
__global__ __launch_bounds__(256) void k_norm(const float* __restrict__ feat,
                                              u8* __restrict__ fb8,
                                              float* __restrict__ selfdot,
                                              float* __restrict__ out) {
    const int gid = blockIdx.x * 256 + threadIdx.x;
    if (gid == 0) out[0] = 0.0f;               // k_final atomicAdds into out
    const int r    = gid >> 6;                 // one wave per row
    const int lane = threadIdx.x & 63;
    const float2 v = ((const float2*)(feat + (size_t)r * DD))[lane];
    float ss = v.x * v.x + v.y * v.y;
#pragma unroll
    for (int off = 1; off < 64; off <<= 1) ss += __shfl_xor(ss, off, 64);
    const float scale = 1.0f / fmaxf(sqrtf(ss), 1e-12f);
    const __hip_fp8_e4m3 qx(v.x * scale), qy(v.y * scale);  // OCP e4m3fn
    const unsigned short pack = (unsigned short)qx.__x |
                                ((unsigned short)qy.__x << 8);
    // lane holds row-bytes 2*lane, 2*lane+1 -> chunk q=lane>>4, h=(lane>>3)&1
    const int g    = r >> 4;
    const int n15r = r & 15;
    const int qc   = lane >> 4;
    const int hc   = (lane >> 3) & 1;
    const int bofs = (2 * lane) & 15;
    *(unsigned short*)(fb8 + (size_t)g * 2048 + hc * 1024 +
                       ((qc * 16 + n15r) << 4) + bofs) = pack;
    // self-dot of the QUANTIZED row (matches the MFMA diagonal)
    const float xb = (float)qx, yb = (float)qy;
    float s2 = xb * xb + yb * yb;
#pragma unroll
    for (int off = 1; off < 64; off <<= 1) s2 += __shfl_xor(s2, off, 64);
    if (lane == 0) selfdot[r] = s2;
}

// ---- kernel 2: F*F^T via MX-fp8 K=128 MFMA, fused exp + masked-possum ----
// Block: 128 rows x 256 cols; 4 waves of 32 rows. Grid 2048 = 64 rb x 32 js.
__global__ __launch_bounds__(256, 4) void k_main(const u8* __restrict__ fb8,
                                                 const int* __restrict__ labels,
                                                 float* __restrict__ g_se,
                                                 float* __restrict__ g_ps) {
    __shared__ int slab[256];          // labels of this block's col range

    const int tid  = threadIdx.x;
    const int lane = tid & 63;
    const int w    = tid >> 6;                  // 0..3
    const int rb   = blockIdx.x >> 5;           // 0..63
    const int js   = blockIdx.x & (NSPLIT - 1); // 0..31
    const int i0   = rb * 128 + w * 32;
    const int jb0  = js * 256;
    const int q    = lane >> 4;
    const int n15  = lane & 15;

    slab[tid] = labels[(jb0 + tid) & (NB - 1)];

    // A fragments: 2 row-tiles, full K=128 per tile (8 VGPRs each)
    v8i af[2];
#pragma unroll
    for (int tt = 0; tt < 2; ++tt) {
        const u8* ap = fb8 + (size_t)((i0 >> 4) + tt) * 2048 + lane * 16;
        const v4i lo = *(const v4i*)ap;
        const v4i hi = *(const v4i*)(ap + 1024);
        v8i a;
#pragma unroll
        for (int k = 0; k < 4; ++k) { a[k] = lo[k]; a[4 + k] = hi[k]; }
        af[tt] = a;
    }
    // labels of this lane's 8 accumulator rows (C/D map: row = q*4+r)
    int labi[8];
#pragma unroll
    for (int tt = 0; tt < 2; ++tt)
#pragma unroll
        for (int r = 0; r < 4; ++r)
            labi[tt * 4 + r] = labels[(i0 + tt * 16 + q * 4 + r) & (NB - 1)];

    float a_se[8] = {}, a_ps[8] = {};

    __syncthreads();   // slab ready (only barrier in the kernel)

    const u8* bbase = fb8 + (size_t)(jb0 >> 4) * 2048 + lane * 16;
#pragma unroll 4
    for (int jt = 0; jt < 16; ++jt) {
        const u8* bp = bbase + (size_t)jt * 2048;
        const v4i lo = *(const v4i*)bp;
        const v4i hi = *(const v4i*)(bp + 1024);
        v8i bb;
#pragma unroll
        for (int k = 0; k < 4; ++k) { bb[k] = lo[k]; bb[4 + k] = hi[k]; }
        const int labj = slab[jt * 16 + n15];
        f32x4 a0 = {0.f, 0.f, 0.f, 0.f}, a1 = {0.f, 0.f, 0.f, 0.f};
        // cbsz=0 (A=fp8 e4m3), blgp=0 (B=fp8); scale bytes 0x7F = e8m0 1.0
        a0 = __builtin_amdgcn_mfma_scale_f32_16x16x128_f8f6f4(
                 af[0], bb, a0, 0, 0, 0, 0x7F7F7F7F, 0, 0x7F7F7F7F);
        a1 = __builtin_amdgcn_mfma_scale_f32_16x16x128_f8f6f4(
                 af[1], bb, a1, 0, 0, 0, 0x7F7F7F7F, 0, 0x7F7F7F7F);
#pragma unroll
        for (int r = 0; r < 4; ++r) {
            const float d0 = a0[r], d1 = a1[r];
            a_se[r]     += __builtin_amdgcn_exp2f(fmaf(d0, EC1, EC0));
            a_se[4 + r] += __builtin_amdgcn_exp2f(fmaf(d1, EC1, EC0));
            a_ps[r]     += (labi[r]     == labj) ? d0 : 0.0f;  // raw dot; shifted in k_final
            a_ps[4 + r] += (labi[4 + r] == labj) ? d1 : 0.0f;
        }
    }

    // 16 lanes per quad share the same rows; reduce, single plain store each
#pragma unroll
    for (int s = 0; s < 8; ++s) {
        float v1 = a_se[s], v2 = a_ps[s];
#pragma unroll
        for (int off = 1; off < 16; off <<= 1) {
            v1 += __shfl_xor(v1, off, 64);
            v2 += __shfl_xor(v2, off, 64);
        }
        if (n15 == 0) {
            const int row = i0 + (s >> 2) * 16 + q * 4 + (s & 3);
            g_se[js * NN + row] = v1;
            g_ps[js * NN + row] = v2;
        }
    }
}

// ---- kernel 3: per-row loss; counts via LDS histogram; atomic mean ----
__global__ __launch_bounds__(256) void k_final(const int* __restrict__ labels,
                                               const float* __restrict__ g_se,
                                               const float* __restrict__ g_ps,
                                               const float* __restrict__ selfdot,
                                               float* __restrict__ out) {
    __shared__ int hist[NCLS];
    const int tid = threadIdx.x;
    for (int i = tid; i < NCLS; i += 256) hist[i] = 0;
    __syncthreads();
    for (int b = tid; b < NB; b += 256) atomicAdd(&hist[labels[b]], 1);
    __syncthreads();

    const int r = blockIdx.x * 256 + tid;
    const int c = labels[r & (NB - 1)];
    float se = 0.f, ps = 0.f;
#pragma unroll
    for (int t = 0; t < NSPLIT; ++t) {
        se += g_se[t * NN + r];
        ps += g_ps[t * NN + r];
    }
    const float sd = selfdot[r];
    se -= __builtin_amdgcn_exp2f(fmaf(sd, EC1, EC0));  // drop diagonal from sumexp
    const float ct = (float)(2 * hist[c] - 1);         // positives excl. diagonal
    const float possum = INV_T * ((ps - sd) - ct);     // sum_pos (l_ij - M)
    const float lg  = __builtin_amdgcn_logf(se + 1e-12f) * LN2;
    const float mlpp = (possum - ct * lg) / fmaxf(ct, 1.0f);
    float v = -mlpp * (1.0f / (float)NN);
#pragma unroll
    for (int off = 1; off < 64; off <<= 1) v += __shfl_xor(v, off, 64);
    __shared__ float sred[4];
    if ((tid & 63) == 0) sred[tid >> 6] = v;
    __syncthreads();
    if (tid == 0) atomicAdd(out, sred[0] + sred[1] + sred[2] + sred[3]);
}

extern "C" void kernel_launch(void* const* d_in, const int* in_sizes, int n_in,
                              void* d_out, int out_size, void* d_ws, size_t ws_size,
                              hipStream_t stream) {
    const float* feat = (const float*)d_in[0];
    const int* labels = (const int*)d_in[1];
    float* out        = (float*)d_out;
    char* ws          = (char*)d_ws;

    u8* fb8         = (u8*)ws;                                       // 1 MB fp8 (fragment-major)
    float* g_se     = (float*)(ws + (size_t)1 * 1024 * 1024);        // [32][NN] 1 MB
    float* g_ps     = g_se + NSPLIT * NN;                            // 1 MB
    float* selfdot  = g_ps + NSPLIT * NN;                            // NN f32

    k_norm<<<NN / 4, 256, 0, stream>>>(feat, fb8, selfdot, out);
    k_main<<<(NN / 128) * NSPLIT, 256, 0, stream>>>(fb8, labels, g_se, g_ps);
    k_final<<<NN / 256, 256, 0, stream>>>(labels, g_se, g_ps, selfdot, out);
}

// Round 8
// 82.843 us; speedup vs baseline: 4.3286x; 1.1470x over previous
//
#include <hip/hip_runtime.h>
#include <hip/hip_bf16.h>
#include <hip/hip_fp8.h>
#include <math.h>

#define NB 4096     // batch (= B); label of row n is labels[n % NB]
#define NN 8192     // N = B * n_views
#define DD 128      // feature dim (bytes per fp8 row)
#define NCLS 100    // label values 0..99
#define NSPLIT 16   // j-splits; 512 cols per block (R2-verified best)

constexpr float INV_T = 14.285714285714286f;   // 1/0.07 (= subtracted row max M)
constexpr float EC1   = 20.609929155556620f;   // INV_T * log2(e)
constexpr float EC0   = -20.609929155556620f;  // -INV_T * log2(e)
constexpr float LN2   = 0.6931471805599453f;

typedef unsigned char u8;
typedef __attribute__((ext_vector_type(8))) int   v8i;
typedef __attribute__((ext_vector_type(4))) int   v4i;
typedef __attribute__((ext_vector_type(4))) float f32x4;

// fb8 layout is FRAGMENT-MAJOR: 512 groups of 16 rows; group g occupies 2 KB:
//   fb8[g*2048 + h*1024 + (q*16 + n15)*16 + b]
//     = normalized_row(g*16 + n15)[ q*32 + h*16 + b ],  q=0..3, h=0..1, b=0..15
// MFMA A/B operand for row-group g = two coalesced 1KB loads (lane l reads
// base + l*16 and +1024). fb8 is 1 MB, fully L2-resident; no LDS staging.
//
// Split accumulators are [NN][NSPLIT] (row-major): k_main scalar-stores
// g_se[row*16+js]; k_final gathers one row as 4 contiguous float4 loads.

// ---- kernel 1: L2-normalize rows -> fp8 e4m3 (fragment-major) + selfdot ----
__global__ __launch_bounds__(256) void k_norm(const float* __restrict__ feat,
                                              u8* __restrict__ fb8,
                                              float* __restrict__ selfdot,
                                              float* __restrict__ out) {
    const int gid = blockIdx.x * 256 + threadIdx.x;
    if (gid == 0) out[0] = 0.0f;               // k_final atomicAdds into out
    const int r    = gid >> 6;                 // one wave per row
    const int lane = threadIdx.x & 63;
    const float2 v = ((const float2*)(feat + (size_t)r * DD))[lane];
    float ss = v.x * v.x + v.y * v.y;
#pragma unroll
    for (int off = 1; off < 64; off <<= 1) ss += __shfl_xor(ss, off, 64);
    const float scale = 1.0f / fmaxf(sqrtf(ss), 1e-12f);
    const __hip_fp8_e4m3 qx(v.x * scale), qy(v.y * scale);  // OCP e4m3fn
    const unsigned short pack = (unsigned short)qx.__x |
                                ((unsigned short)qy.__x << 8);
    // lane holds row-bytes 2*lane, 2*lane+1 -> chunk q=lane>>4, h=(lane>>3)&1
    const int g    = r >> 4;
    const int n15r = r & 15;
    const int qc   = lane >> 4;
    const int hc   = (lane >> 3) & 1;
    const int bofs = (2 * lane) & 15;
    *(unsigned short*)(fb8 + (size_t)g * 2048 + hc * 1024 +
                       ((qc * 16 + n15r) << 4) + bofs) = pack;
    // self-dot of the QUANTIZED row (matches the MFMA diagonal)
    const float xb = (float)qx, yb = (float)qy;
    float s2 = xb * xb + yb * yb;
#pragma unroll
    for (int off = 1; off < 64; off <<= 1) s2 += __shfl_xor(s2, off, 64);
    if (lane == 0) selfdot[r] = s2;
}

// ---- kernel 2: F*F^T via MX-fp8 K=128 MFMA, fused exp + masked-possum ----
// Block: 128 rows x 512 cols; 4 waves of 32 rows. Grid 1024 = 64 rb x 16 js.
// Inner loop identical to the R2-verified version (80.8 us total).
__global__ __launch_bounds__(256, 4) void k_main(const u8* __restrict__ fb8,
                                                 const int* __restrict__ labels,
                                                 float* __restrict__ g_se,
                                                 float* __restrict__ g_ps) {
    __shared__ int slab[512];          // labels of this block's col range
    __shared__ int rlab[128];          // labels of this block's row range

    const int tid  = threadIdx.x;
    const int lane = tid & 63;
    const int w    = tid >> 6;                  // 0..3
    const int rb   = blockIdx.x >> 4;           // 0..63
    const int js   = blockIdx.x & (NSPLIT - 1); // 0..15
    const int i0   = rb * 128 + w * 32;
    const int jb0  = js * 512;
    const int q    = lane >> 4;
    const int n15  = lane & 15;

    slab[tid]       = labels[(jb0 + tid) & (NB - 1)];
    slab[tid + 256] = labels[(jb0 + tid + 256) & (NB - 1)];
    if (tid < 128) rlab[tid] = labels[(rb * 128 + tid) & (NB - 1)];

    // A fragments: 2 row-tiles, full K=128 per tile (8 VGPRs each)
    v8i af[2];
#pragma unroll
    for (int tt = 0; tt < 2; ++tt) {
        const u8* ap = fb8 + (size_t)((i0 >> 4) + tt) * 2048 + lane * 16;
        const v4i lo = *(const v4i*)ap;
        const v4i hi = *(const v4i*)(ap + 1024);
        v8i a;
#pragma unroll
        for (int k = 0; k < 4; ++k) { a[k] = lo[k]; a[4 + k] = hi[k]; }
        af[tt] = a;
    }

    __syncthreads();   // slab/rlab ready (only barrier in the kernel)

    // labels of this lane's 8 accumulator rows (C/D map: row = q*4+r)
    int labi[8];
#pragma unroll
    for (int tt = 0; tt < 2; ++tt)
#pragma unroll
        for (int r = 0; r < 4; ++r)
            labi[tt * 4 + r] = rlab[w * 32 + tt * 16 + q * 4 + r];

    float a_se[8] = {}, a_ps[8] = {};

    const u8* bbase = fb8 + (size_t)(jb0 >> 4) * 2048 + lane * 16;
#pragma unroll 4
    for (int jt = 0; jt < 32; ++jt) {
        const u8* bp = bbase + (size_t)jt * 2048;
        const v4i lo = *(const v4i*)bp;
        const v4i hi = *(const v4i*)(bp + 1024);
        v8i bb;
#pragma unroll
        for (int k = 0; k < 4; ++k) { bb[k] = lo[k]; bb[4 + k] = hi[k]; }
        const int labj = slab[jt * 16 + n15];
        f32x4 a0 = {0.f, 0.f, 0.f, 0.f}, a1 = {0.f, 0.f, 0.f, 0.f};
        // cbsz=0 (A=fp8 e4m3), blgp=0 (B=fp8); scale bytes 0x7F = e8m0 1.0
        a0 = __builtin_amdgcn_mfma_scale_f32_16x16x128_f8f6f4(
                 af[0], bb, a0, 0, 0, 0, 0x7F7F7F7F, 0, 0x7F7F7F7F);
        a1 = __builtin_amdgcn_mfma_scale_f32_16x16x128_f8f6f4(
                 af[1], bb, a1, 0, 0, 0, 0x7F7F7F7F, 0, 0x7F7F7F7F);
#pragma unroll
        for (int r = 0; r < 4; ++r) {
            const float d0 = a0[r], d1 = a1[r];
            a_se[r]     += __builtin_amdgcn_exp2f(fmaf(d0, EC1, EC0));
            a_se[4 + r] += __builtin_amdgcn_exp2f(fmaf(d1, EC1, EC0));
            a_ps[r]     += (labi[r]     == labj) ? d0 : 0.0f;  // raw dot; shifted in k_final
            a_ps[4 + r] += (labi[4 + r] == labj) ? d1 : 0.0f;
        }
    }

    // 16 lanes per quad share the same rows; reduce, single plain store each
#pragma unroll
    for (int s = 0; s < 8; ++s) {
        float v1 = a_se[s], v2 = a_ps[s];
#pragma unroll
        for (int off = 1; off < 16; off <<= 1) {
            v1 += __shfl_xor(v1, off, 64);
            v2 += __shfl_xor(v2, off, 64);
        }
        if (n15 == 0) {
            const int row = i0 + (s >> 2) * 16 + q * 4 + (s & 3);
            g_se[row * NSPLIT + js] = v1;
            g_ps[row * NSPLIT + js] = v2;
        }
    }
}

// ---- kernel 3: per-row loss; counts via LDS histogram; atomic mean ----
__global__ __launch_bounds__(256) void k_final(const int* __restrict__ labels,
                                               const float* __restrict__ g_se,
                                               const float* __restrict__ g_ps,
                                               const float* __restrict__ selfdot,
                                               float* __restrict__ out) {
    __shared__ int hist[NCLS];
    const int tid = threadIdx.x;
    for (int i = tid; i < NCLS; i += 256) hist[i] = 0;
    __syncthreads();
    for (int b = tid; b < NB; b += 256) atomicAdd(&hist[labels[b]], 1);
    __syncthreads();

    const int r = blockIdx.x * 256 + tid;
    const int c = labels[r & (NB - 1)];
    const float4* pse = (const float4*)(g_se + (size_t)r * NSPLIT);
    const float4* pps = (const float4*)(g_ps + (size_t)r * NSPLIT);
    float se = 0.f, ps = 0.f;
#pragma unroll
    for (int t = 0; t < NSPLIT / 4; ++t) {
        const float4 a = pse[t];
        const float4 b = pps[t];
        se += (a.x + a.y) + (a.z + a.w);
        ps += (b.x + b.y) + (b.z + b.w);
    }
    const float sd = selfdot[r];
    se -= __builtin_amdgcn_exp2f(fmaf(sd, EC1, EC0));  // drop diagonal from sumexp
    const float ct = (float)(2 * hist[c] - 1);         // positives excl. diagonal
    const float possum = INV_T * ((ps - sd) - ct);     // sum_pos (l_ij - M)
    const float lg  = __builtin_amdgcn_logf(se + 1e-12f) * LN2;
    const float mlpp = (possum - ct * lg) / fmaxf(ct, 1.0f);
    float v = -mlpp * (1.0f / (float)NN);
#pragma unroll
    for (int off = 1; off < 64; off <<= 1) v += __shfl_xor(v, off, 64);
    __shared__ float sred[4];
    if ((tid & 63) == 0) sred[tid >> 6] = v;
    __syncthreads();
    if (tid == 0) atomicAdd(out, sred[0] + sred[1] + sred[2] + sred[3]);
}

extern "C" void kernel_launch(void* const* d_in, const int* in_sizes, int n_in,
                              void* d_out, int out_size, void* d_ws, size_t ws_size,
                              hipStream_t stream) {
    const float* feat = (const float*)d_in[0];
    const int* labels = (const int*)d_in[1];
    float* out        = (float*)d_out;
    char* ws          = (char*)d_ws;

    u8* fb8         = (u8*)ws;                                       // 1 MB fp8 (fragment-major)
    float* g_se     = (float*)(ws + (size_t)1 * 1024 * 1024);        // [NN][16] 512 KB
    float* g_ps     = g_se + NSPLIT * NN;                            // 512 KB
    float* selfdot  = g_ps + NSPLIT * NN;                            // NN f32

    k_norm<<<NN / 4, 256, 0, stream>>>(feat, fb8, selfdot, out);
    k_main<<<(NN / 128) * NSPLIT, 256, 0, stream>>>(fb8, labels, g_se, g_ps);
    k_final<<<NN / 256, 256, 0, stream>>>(labels, g_se, g_ps, selfdot, out);
}